// Round 7
// baseline (398.178 us; speedup 1.0000x reference)
//
#include <hip/hip_runtime.h>
#include <float.h>
#include <math.h>

// NormEMAVectorQuantizer via split-bf16 MFMA + exact fp32 refinement.
// z (8,2048,256) f32, weight (8192,256) f32 (unit rows).
// out = [ z_q (16384*256) | loss (1) | indices (16384, as float) ]
//
// Round-7 k_coarse: 256x256, BK=64, 8 waves (2Mx4N), double-buffer 128KB.
// AITER-style K-tile: ONE barrier + vmcnt(0) at entry; 16 MFMA groups of 4,
// each gated by a COUNTED lgkmcnt (never 0 until tile end); k1 fragment
// reads + staging gld16 interleaved among the k0 MFMA groups so the LDS
// queue drains under the matrix pipe. ds_read offset: immediates cut addr
// VGPRs. Epilogue = 16-lane shfl reduce + small LDS merge.

#define BT_ 16384
#define D_  256
#define N_  8192
#define BETA_ 1.0f
#define THR_ 5e-4f

#define BM 256
#define BN 256
#define NKT 12           // 768 / 64 K-tiles
#define NTILES 32        // N_ / BN

typedef __attribute__((ext_vector_type(8))) short bf16x8;
typedef __attribute__((ext_vector_type(4))) float f32x4;

__device__ __forceinline__ void gld16(void* lds, const void* g) {
  __builtin_amdgcn_global_load_lds(
      (const __attribute__((address_space(1))) void*)g,
      (__attribute__((address_space(3))) void*)lds, 16, 0, 0);
}

__device__ __forceinline__ unsigned short f2bf(float x) {
  unsigned u = __float_as_uint(x);
  u += 0x7FFFu + ((u >> 16) & 1u);
  return (unsigned short)(u >> 16);
}
__device__ __forceinline__ float bf2f(unsigned short h) {
  return __uint_as_float(((unsigned)h) << 16);
}

// ---------------- kernel 1: normalize z, store zn + split A_cat ----------------
__global__ __launch_bounds__(256) void k_prep_z(const float* __restrict__ z,
                                                float* __restrict__ zn,
                                                ushort* __restrict__ Acat) {
  const int row  = blockIdx.x * 4 + (threadIdx.x >> 6);
  const int lane = threadIdx.x & 63;
  float4 v = *(reinterpret_cast<const float4*>(z) + (size_t)row * 64 + lane);
  float s = v.x * v.x + v.y * v.y + v.z * v.z + v.w * v.w;
#pragma unroll
  for (int o = 32; o > 0; o >>= 1) s += __shfl_xor(s, o, 64);
  float dn = fmaxf(sqrtf(s), 1e-12f);
  v.x /= dn; v.y /= dn; v.z /= dn; v.w /= dn;
  *(reinterpret_cast<float4*>(zn) + (size_t)row * 64 + lane) = v;
  ushort4 h  = make_ushort4(f2bf(v.x), f2bf(v.y), f2bf(v.z), f2bf(v.w));
  ushort4 lo = make_ushort4(f2bf(v.x - bf2f(h.x)), f2bf(v.y - bf2f(h.y)),
                            f2bf(v.z - bf2f(h.z)), f2bf(v.w - bf2f(h.w)));
  ushort4* A4 = reinterpret_cast<ushort4*>(Acat);
  size_t rb = (size_t)row * 192 + lane;   // 768/4 = 192 ushort4 per row
  A4[rb]       = h;    // zh
  A4[rb + 64]  = h;    // zh
  A4[rb + 128] = lo;   // zl
}

// ---------------- kernel 2: wn2, split B_cat ----------------
__global__ __launch_bounds__(256) void k_prep_w(const float* __restrict__ w,
                                                float* __restrict__ wn2,
                                                ushort* __restrict__ Bcat) {
  const int row  = blockIdx.x * 4 + (threadIdx.x >> 6);
  const int lane = threadIdx.x & 63;
  float4 v = *(reinterpret_cast<const float4*>(w) + (size_t)row * 64 + lane);
  float s = v.x * v.x + v.y * v.y + v.z * v.z + v.w * v.w;
#pragma unroll
  for (int o = 32; o > 0; o >>= 1) s += __shfl_xor(s, o, 64);
  if (lane == 0) wn2[row] = s;
  ushort4 h  = make_ushort4(f2bf(v.x), f2bf(v.y), f2bf(v.z), f2bf(v.w));
  ushort4 lo = make_ushort4(f2bf(v.x - bf2f(h.x)), f2bf(v.y - bf2f(h.y)),
                            f2bf(v.z - bf2f(h.z)), f2bf(v.w - bf2f(h.w)));
  ushort4* B4 = reinterpret_cast<ushort4*>(Bcat);
  size_t rb = (size_t)row * 192 + lane;
  B4[rb]       = h;    // wh
  B4[rb + 64]  = lo;   // wl
  B4[rb + 128] = h;    // wh
}

// ---------------- kernel 3: counted-wait MFMA GEMM, 256x256, BK=64 ----------
// grid = 2048 blocks, 512 threads (8 waves, 2M x 4N, 128x64 out each).
// LDS (dynamic 128KB): A bufs @0,@32K; B bufs @64K,@96K. [256 rows][128B].
// Swizzle: LDS[r][g16] = G[r][g16 ^ (r&7)] (both sides, r2-proven).
#define SB0 __builtin_amdgcn_sched_barrier(0)
#define LGKM(n) asm volatile("s_waitcnt lgkmcnt(" #n ")" ::: "memory")
#define DSR(dst, base, off) \
  asm volatile("ds_read_b128 %0, %1 offset:" #off : "=&v"(dst) : "v"(base))
#define MF4K0(M)                                                               \
  acc[M][0] = __builtin_amdgcn_mfma_f32_16x16x32_bf16(af0[M], bg0[0], acc[M][0], 0, 0, 0); \
  acc[M][1] = __builtin_amdgcn_mfma_f32_16x16x32_bf16(af0[M], bg0[1], acc[M][1], 0, 0, 0); \
  acc[M][2] = __builtin_amdgcn_mfma_f32_16x16x32_bf16(af0[M], bg0[2], acc[M][2], 0, 0, 0); \
  acc[M][3] = __builtin_amdgcn_mfma_f32_16x16x32_bf16(af0[M], bg0[3], acc[M][3], 0, 0, 0)
#define MF4K1(M)                                                               \
  acc[M][0] = __builtin_amdgcn_mfma_f32_16x16x32_bf16(af1[M], bg1[0], acc[M][0], 0, 0, 0); \
  acc[M][1] = __builtin_amdgcn_mfma_f32_16x16x32_bf16(af1[M], bg1[1], acc[M][1], 0, 0, 0); \
  acc[M][2] = __builtin_amdgcn_mfma_f32_16x16x32_bf16(af1[M], bg1[2], acc[M][2], 0, 0, 0); \
  acc[M][3] = __builtin_amdgcn_mfma_f32_16x16x32_bf16(af1[M], bg1[3], acc[M][3], 0, 0, 0)
#define PRIO1 __builtin_amdgcn_s_setprio(1)
#define PRIO0 __builtin_amdgcn_s_setprio(0)

__global__ __launch_bounds__(512, 2) void k_coarse(const ushort* __restrict__ Acat,
                                                   const ushort* __restrict__ Bcat,
                                                   const float* __restrict__ wn2,
                                                   float* __restrict__ tm,
                                                   float* __restrict__ ts,
                                                   int* __restrict__ ti) {
  extern __shared__ char smem[];
  const unsigned sbase = (unsigned)(size_t)(void*)smem & 0x3ffffu;

  const int tid = threadIdx.x;
  const int l   = tid & 63;
  const int wv  = tid >> 6;
  const int wr  = wv >> 2;       // 0..1 -> rows wr*128
  const int wc  = wv & 3;        // 0..3 -> cols wc*64
  // XCD-aware 2D-chunked swizzle (r4-proven: FETCH 427->142MB)
  const int bid  = blockIdx.x;
  const int xcd  = bid & 7;
  const int q    = bid >> 3;
  const int chnk = q >> 5, wq = q & 31;
  const int rt   = xcd * 8 + (chnk >> 2) * 4 + (wq >> 3);
  const int ct   = (chnk & 3) * 8 + (wq & 7);
  const int row0 = rt * BM;
  const int col0 = ct * BN;

  // staging source (pre-swizzled): wave wv stages rows [u*64+wv*8, +8)/unit;
  // lane l -> row +(l>>3), source 16B-granule (l&7)^(l>>3).
  const int srow = l >> 3;
  const int sg   = ((l & 7) ^ srow) * 16;
  const char* aS = (const char*)Acat + (size_t)(row0 + wv * 8 + srow) * 1536 + sg;
  const char* bS = (const char*)Bcat + (size_t)(col0 + wv * 8 + srow) * 1536 + sg;

  // fragment read bases: row R byte base R*128; granule swizzled by (R&7)
  const int lA   = l & 15;
  const int kswz = (lA & 7) << 4;
  const int kof0 = ((l >> 4) * 16) ^ kswz;
  const int kof1 = (((l >> 4) * 16) + 64) ^ kswz;
  unsigned aK0 = sbase + (unsigned)((wr * 128 + lA) * 128) + (unsigned)kof0;
  unsigned aK1 = sbase + (unsigned)((wr * 128 + lA) * 128) + (unsigned)kof1;
  unsigned bK0 = sbase + 65536u + (unsigned)((wc * 64 + lA) * 128) + (unsigned)kof0;
  unsigned bK1 = sbase + 65536u + (unsigned)((wc * 64 + lA) * 128) + (unsigned)kof1;

  f32x4 acc[8][4];
#pragma unroll
  for (int i = 0; i < 8; ++i)
#pragma unroll
    for (int j = 0; j < 4; ++j) acc[i][j] = (f32x4){0.f, 0.f, 0.f, 0.f};

  // prologue: stage tile 0 (A0 + B0, 8 gld16)
#pragma unroll
  for (int u = 0; u < 4; ++u) {
    gld16(smem + u * 8192 + wv * 1024,          aS + (size_t)u * 98304);
    gld16(smem + 65536 + u * 8192 + wv * 1024,  bS + (size_t)u * 98304);
  }

  for (int t = 0; t < NKT; ++t) {
    // entry: own stage(t) drained; barrier makes all waves' stage visible.
    asm volatile("s_waitcnt vmcnt(0)" ::: "memory");
    SB0;
    __builtin_amdgcn_s_barrier();
    SB0;

    bf16x8 bg0[4], af0[8], bg1[4], af1[8];
    // k0 fragment reads: DS issue order = bg0[0..3] (#1-4), af0[0..7] (#5-12)
    DSR(bg0[0], bK0, 0);     DSR(bg0[1], bK0, 2048);
    DSR(bg0[2], bK0, 4096);  DSR(bg0[3], bK0, 6144);
    DSR(af0[0], aK0, 0);     DSR(af0[1], aK0, 2048);
    DSR(af0[2], aK0, 4096);  DSR(af0[3], aK0, 6144);
    DSR(af0[4], aK0, 8192);  DSR(af0[5], aK0, 10240);
    DSR(af0[6], aK0, 12288); DSR(af0[7], aK0, 14336);

    const int tn = t + 1;
    const bool st = tn < NKT;
    char* dA = smem + (tn & 1) * 32768;
    char* dB = dA + 65536;
    const char* sA = aS + (size_t)tn * 128;
    const char* sB = bS + (size_t)tn * 128;
    if (st) { gld16(dA + wv * 1024, sA);
              gld16(dA + 8192 + wv * 1024, sA + 98304); }

    // k0 cluster: counted waits (issued so far I; need first (5+M) done)
    LGKM(7);  SB0; PRIO1; MF4K0(0); PRIO0;                  // I=12, need 5
    if (st) { gld16(dA + 16384 + wv * 1024, sA + 196608);
              gld16(dA + 24576 + wv * 1024, sA + 294912); }
    LGKM(6);  SB0; PRIO1; MF4K0(1); PRIO0;                  // I=12, need 6
    DSR(bg1[0], bK1, 0);     DSR(bg1[1], bK1, 2048);        // I=14
    if (st) { gld16(dB + wv * 1024, sB);
              gld16(dB + 8192 + wv * 1024, sB + 98304); }
    LGKM(7);  SB0; PRIO1; MF4K0(2); PRIO0;                  // need 7
    DSR(bg1[2], bK1, 4096);  DSR(bg1[3], bK1, 6144);        // I=16
    if (st) { gld16(dB + 16384 + wv * 1024, sB + 196608);
              gld16(dB + 24576 + wv * 1024, sB + 294912); }
    LGKM(8);  SB0; PRIO1; MF4K0(3); PRIO0;                  // need 8
    DSR(af1[0], aK1, 0);     DSR(af1[1], aK1, 2048);        // I=18
    LGKM(9);  SB0; PRIO1; MF4K0(4); PRIO0;                  // need 9
    DSR(af1[2], aK1, 4096);  DSR(af1[3], aK1, 6144);        // I=20
    LGKM(10); SB0; PRIO1; MF4K0(5); PRIO0;                  // need 10
    DSR(af1[4], aK1, 8192);  DSR(af1[5], aK1, 10240);       // I=22
    LGKM(11); SB0; PRIO1; MF4K0(6); PRIO0;                  // need 11
    DSR(af1[6], aK1, 12288); DSR(af1[7], aK1, 14336);       // I=24
    LGKM(12); SB0; PRIO1; MF4K0(7); PRIO0;                  // need 12
    // k1 cluster: need bg1 (#13-16) + af1[M] (#17+M)
    LGKM(7);  SB0; PRIO1; MF4K1(0); PRIO0;
    LGKM(6);  SB0; PRIO1; MF4K1(1); PRIO0;
    LGKM(5);  SB0; PRIO1; MF4K1(2); PRIO0;
    LGKM(4);  SB0; PRIO1; MF4K1(3); PRIO0;
    LGKM(3);  SB0; PRIO1; MF4K1(4); PRIO0;
    LGKM(2);  SB0; PRIO1; MF4K1(5); PRIO0;
    LGKM(1);  SB0; PRIO1; MF4K1(6); PRIO0;
    LGKM(0);  SB0; PRIO1; MF4K1(7); PRIO0;

    aK0 ^= 32768u; aK1 ^= 32768u; bK0 ^= 32768u; bK1 ^= 32768u;
  }

  // -------- epilogue: per-thread j-min, 16-lane shfl reduce, LDS merge -----
  float wnv[4];
#pragma unroll
  for (int n = 0; n < 4; ++n) wnv[n] = wn2[col0 + wc * 64 + n * 16 + lA];
  float4* red4 = (float4*)smem;    // [256][4] = 16 KB (A0 region, free)

#pragma unroll
  for (int i = 0; i < 8; ++i) {
#pragma unroll
    for (int qq = 0; qq < 4; ++qq) {
      float m = FLT_MAX, s = FLT_MAX; int c = 0;
#pragma unroll
      for (int j = 0; j < 4; ++j) {
        float d = fmaf(-2.0f, acc[i][j][qq], wnv[j]);
        int cc = wc * 64 + j * 16 + lA;
        if (d < m) { s = m; m = d; c = cc; }
        else if (d < s) s = d;
      }
#pragma unroll
      for (int msk = 1; msk < 16; msk <<= 1) {
        float om = __shfl_xor(m, msk, 64);
        float os = __shfl_xor(s, msk, 64);
        int   oc = __shfl_xor(c, msk, 64);
        float ns = fminf(fminf(s, os), fmaxf(m, om));
        if (om < m || (om == m && oc < c)) { m = om; c = oc; }
        s = ns;
      }
      if (lA == 0) {
        int row = wr * 128 + i * 16 + (l >> 4) * 4 + qq;
        red4[row * 4 + wc] = (float4){m, s, __int_as_float(c), 0.f};
      }
    }
  }
  __syncthreads();
  if (tid < 256) {
    float4 e = red4[tid * 4];
    float gm = e.x, gs = e.y; int gc = __float_as_int(e.z);
#pragma unroll
    for (int k = 1; k < 4; ++k) {
      float4 ek = red4[tid * 4 + k];
      float om = ek.x, os = ek.y; int oc = __float_as_int(ek.z);
      float ns = fminf(fminf(gs, os), fmaxf(gm, om));
      if (om < gm || (om == gm && oc < gc)) { gm = om; gc = oc; }
      gs = ns;
    }
    size_t o = (size_t)ct * BT_ + row0 + tid;
    tm[o] = gm; ts[o] = gs; ti[o] = col0 + gc;
  }
}

// ---------------- kernel 4: combine tiles per row, flag ambiguous ----------------
__global__ __launch_bounds__(256) void k_combine(const float* __restrict__ tm,
                                                 const float* __restrict__ ts,
                                                 const int* __restrict__ ti,
                                                 int* __restrict__ idxf,
                                                 int* __restrict__ flagged,
                                                 int* __restrict__ count) {
  const int row = blockIdx.x * 256 + threadIdx.x;
  float m = FLT_MAX, s = FLT_MAX; int bi = 0x7fffffff;
  for (int t = 0; t < NTILES; ++t) {
    size_t o = (size_t)t * BT_ + row;
    float om = tm[o], os = ts[o]; int oi = ti[o];
    float nsv = fminf(fminf(s, os), fmaxf(m, om));
    if (om < m || (om == m && oi < bi)) { m = om; bi = oi; }
    s = nsv;
  }
  idxf[row] = bi;
  if (s - m <= THR_) {
    int p = atomicAdd(count, 1);
    flagged[p] = row;
  }
}

// ---------------- kernel 5: exact fp32 refinement of flagged rows ----------------
__global__ __launch_bounds__(128) void k_refine(const float* __restrict__ zn,
                                                const float* __restrict__ w,
                                                const float* __restrict__ wn2,
                                                const float* __restrict__ tm,
                                                const int* __restrict__ flagged,
                                                const int* __restrict__ count,
                                                int* __restrict__ idxf) {
  __shared__ float4 znr[64];
  __shared__ float tmr[32];
  __shared__ float m1s;
  __shared__ float wd[2];
  __shared__ int   wi[2];
  const int tid = threadIdx.x;
  const int cnt = *count;
  for (int f = blockIdx.x; f < cnt; f += gridDim.x) {
    __syncthreads();   // protect LDS reuse across iterations
    const int row = flagged[f];
    if (tid < 64) {
      znr[tid] = *(reinterpret_cast<const float4*>(zn) + (size_t)row * 64 + tid);
    }
    if (tid < 32) {
      float tv = tm[(size_t)tid * BT_ + row];
      tmr[tid] = tv;
      float mm = tv;
#pragma unroll
      for (int msk = 16; msk > 0; msk >>= 1) mm = fminf(mm, __shfl_xor(mm, msk, 64));
      if (tid == 0) m1s = mm;
    }
    __syncthreads();
    const float lim = m1s + THR_;
    float bd = FLT_MAX; int bi = 0x7fffffff;
    for (int t = 0; t < NTILES; ++t) {
      if (tmr[t] <= lim) {
#pragma unroll
        for (int h = 0; h < 2; ++h) {
          int c = t * BN + h * 128 + tid;
          const float4* wr4 = reinterpret_cast<const float4*>(w) + (size_t)c * 64;
          float d0 = 0.f, d1 = 0.f, d2 = 0.f, d3 = 0.f;
#pragma unroll
          for (int k4 = 0; k4 < 16; ++k4) {
            float4 a0 = znr[k4 * 4 + 0], b0 = wr4[k4 * 4 + 0];
            float4 a1 = znr[k4 * 4 + 1], b1 = wr4[k4 * 4 + 1];
            float4 a2 = znr[k4 * 4 + 2], b2 = wr4[k4 * 4 + 2];
            float4 a3 = znr[k4 * 4 + 3], b3 = wr4[k4 * 4 + 3];
            d0 = fmaf(a0.x, b0.x, d0); d0 = fmaf(a0.y, b0.y, d0);
            d0 = fmaf(a0.z, b0.z, d0); d0 = fmaf(a0.w, b0.w, d0);
            d1 = fmaf(a1.x, b1.x, d1); d1 = fmaf(a1.y, b1.y, d1);
            d1 = fmaf(a1.z, b1.z, d1); d1 = fmaf(a1.w, b1.w, d1);
            d2 = fmaf(a2.x, b2.x, d2); d2 = fmaf(a2.y, b2.y, d2);
            d2 = fmaf(a2.z, b2.z, d2); d2 = fmaf(a2.w, b2.w, d2);
            d3 = fmaf(a3.x, b3.x, d3); d3 = fmaf(a3.y, b3.y, d3);
            d3 = fmaf(a3.z, b3.z, d3); d3 = fmaf(a3.w, b3.w, d3);
          }
          float dot = (d0 + d1) + (d2 + d3);
          float d = fmaf(-2.0f, dot, wn2[c]);
          if (d < bd || (d == bd && c < bi)) { bd = d; bi = c; }
        }
      }
    }
#pragma unroll
    for (int msk = 1; msk < 64; msk <<= 1) {
      float od = __shfl_xor(bd, msk, 64);
      int   oi = __shfl_xor(bi, msk, 64);
      if (od < bd || (od == bd && oi < bi)) { bd = od; bi = oi; }
    }
    if ((tid & 63) == 0) { wd[tid >> 6] = bd; wi[tid >> 6] = bi; }
    __syncthreads();
    if (tid == 0) {
      float fd = wd[0]; int fi = wi[0];
      if (wd[1] < fd || (wd[1] == fd && wi[1] < fi)) { fd = wd[1]; fi = wi[1]; }
      idxf[row] = fi;
    }
  }
}

// ---------------- kernel 6: gather + loss partials (atomic-free) ----------------
__global__ __launch_bounds__(256) void k_gather(const float* __restrict__ zn,
                                                const float* __restrict__ w,
                                                const int* __restrict__ idxf,
                                                float* __restrict__ zq,
                                                float* __restrict__ idx_out,
                                                float* __restrict__ wpart) {
  const int row  = blockIdx.x * 4 + (threadIdx.x >> 6);
  const int lane = threadIdx.x & 63;
  const int bi = idxf[row];
  float4 cv = *(reinterpret_cast<const float4*>(w)  + (size_t)bi  * 64 + lane);
  float4 zv = *(reinterpret_cast<const float4*>(zn) + (size_t)row * 64 + lane);
  *(reinterpret_cast<float4*>(zq) + (size_t)row * 64 + lane) = cv;
  float dx = cv.x - zv.x, dy = cv.y - zv.y, dz = cv.z - zv.z, dw = cv.w - zv.w;
  float s = dx * dx + dy * dy + dz * dz + dw * dw;
#pragma unroll
  for (int o = 32; o > 0; o >>= 1) s += __shfl_xor(s, o, 64);
  if (lane == 0) {
    wpart[row] = s;
    idx_out[row] = (float)bi;
  }
}

// ---------------- kernel 7: final loss reduction ----------------
__global__ __launch_bounds__(256) void k_final(const float* __restrict__ wpart,
                                               float* __restrict__ loss_out) {
  __shared__ float wsum[4];
  float s = 0.f;
  for (int i = threadIdx.x; i < BT_; i += 256) s += wpart[i];
#pragma unroll
  for (int o = 32; o > 0; o >>= 1) s += __shfl_xor(s, o, 64);
  if ((threadIdx.x & 63) == 0) wsum[threadIdx.x >> 6] = s;
  __syncthreads();
  if (threadIdx.x == 0)
    loss_out[0] = BETA_ * ((wsum[0] + wsum[1]) + (wsum[2] + wsum[3])) *
                  (1.0f / (float)(BT_ * D_));
}

extern "C" void kernel_launch(void* const* d_in, const int* in_sizes, int n_in,
                              void* d_out, int out_size, void* d_ws, size_t ws_size,
                              hipStream_t stream) {
  const float* z = (const float*)d_in[0];
  const float* w = (const float*)d_in[1];

  float* out      = (float*)d_out;
  float* zq       = out;
  float* loss_out = out + (size_t)BT_ * D_;
  float* idx_out  = loss_out + 1;

  char* wsb = (char*)d_ws;
  float*  zn      = (float*)(wsb);                         // 16 MB
  ushort* Acat    = (ushort*)(wsb + 16777216);             // 24 MB
  ushort* Bcat    = (ushort*)(wsb + 41943040);             // 12 MB
  float*  tm      = (float*)(wsb + 54525952);              // 2 MB used
  float*  ts      = (float*)(wsb + 58720256);              // 2 MB used (reused as wpart)
  int*    ti      = (int*)(wsb + 62914560);                // 2 MB used
  float*  wn2     = (float*)(wsb + 67108864);              // 32 KB
  int*    idxf    = (int*)(wsb + 67141632);                // 64 KB
  int*    flagged = (int*)(wsb + 67207168);                // 64 KB
  int*    count   = (int*)(wsb + 67272704);
  float*  wpart   = ts;   // ts is dead after k_combine

  hipFuncSetAttribute((const void*)k_coarse,
                      hipFuncAttributeMaxDynamicSharedMemorySize, 131072);

  hipMemsetAsync(count, 0, 4, stream);
  k_prep_z<<<BT_ / 4, 256, 0, stream>>>(z, zn, Acat);
  k_prep_w<<<N_ / 4, 256, 0, stream>>>(w, wn2, Bcat);
  k_coarse<<<(BT_ / BM) * NTILES, 512, 131072, stream>>>(Acat, Bcat, wn2, tm, ts, ti);
  k_combine<<<BT_ / 256, 256, 0, stream>>>(tm, ts, ti, idxf, flagged, count);
  k_refine<<<2048, 128, 0, stream>>>(zn, w, wn2, tm, flagged, count, idxf);
  k_gather<<<BT_ / 4, 256, 0, stream>>>(zn, w, idxf, zq, idx_out, wpart);
  k_final<<<1, 256, 0, stream>>>(wpart, loss_out);
}

// Round 8
// 352.759 us; speedup vs baseline: 1.1288x; 1.1288x over previous
//
#include <hip/hip_runtime.h>
#include <float.h>
#include <math.h>

// NormEMAVectorQuantizer via split-bf16 MFMA + exact fp32 refinement.
// z (8,2048,256) f32, weight (8192,256) f32 (unit rows).
// out = [ z_q (16384*256) | loss (1) | indices (16384, as float) ]
//
// Round-8 k_coarse: OCCUPANCY attack. 128x256 tile, BK=32, 8 waves of
// 64x64 output (acc = 64 VGPR), __launch_bounds__(512,4) -> <=128 VGPR ->
// 4 waves/SIMD, 2 blocks/CU (72KB LDS triple-buffer x2 = 144KB). Depth-2
// prefetch (stage t+2 during t), counted vmcnt(3) entry wait, 1 barrier/tile.

#define BT_ 16384
#define D_  256
#define N_  8192
#define BETA_ 1.0f
#define THR_ 5e-4f

#define BM 128
#define BN 256
#define NKT 24           // 768 / 32 K-tiles
#define NTILES 32        // N_ / BN

typedef __attribute__((ext_vector_type(8))) short bf16x8;
typedef __attribute__((ext_vector_type(4))) float f32x4;

__device__ __forceinline__ void gld16(void* lds, const void* g) {
  __builtin_amdgcn_global_load_lds(
      (const __attribute__((address_space(1))) void*)g,
      (__attribute__((address_space(3))) void*)lds, 16, 0, 0);
}

__device__ __forceinline__ unsigned short f2bf(float x) {
  unsigned u = __float_as_uint(x);
  u += 0x7FFFu + ((u >> 16) & 1u);
  return (unsigned short)(u >> 16);
}
__device__ __forceinline__ float bf2f(unsigned short h) {
  return __uint_as_float(((unsigned)h) << 16);
}

// ---------------- kernel 1: normalize z, store zn + split A_cat ----------------
__global__ __launch_bounds__(256) void k_prep_z(const float* __restrict__ z,
                                                float* __restrict__ zn,
                                                ushort* __restrict__ Acat) {
  const int row  = blockIdx.x * 4 + (threadIdx.x >> 6);
  const int lane = threadIdx.x & 63;
  float4 v = *(reinterpret_cast<const float4*>(z) + (size_t)row * 64 + lane);
  float s = v.x * v.x + v.y * v.y + v.z * v.z + v.w * v.w;
#pragma unroll
  for (int o = 32; o > 0; o >>= 1) s += __shfl_xor(s, o, 64);
  float dn = fmaxf(sqrtf(s), 1e-12f);
  v.x /= dn; v.y /= dn; v.z /= dn; v.w /= dn;
  *(reinterpret_cast<float4*>(zn) + (size_t)row * 64 + lane) = v;
  ushort4 h  = make_ushort4(f2bf(v.x), f2bf(v.y), f2bf(v.z), f2bf(v.w));
  ushort4 lo = make_ushort4(f2bf(v.x - bf2f(h.x)), f2bf(v.y - bf2f(h.y)),
                            f2bf(v.z - bf2f(h.z)), f2bf(v.w - bf2f(h.w)));
  ushort4* A4 = reinterpret_cast<ushort4*>(Acat);
  size_t rb = (size_t)row * 192 + lane;   // 768/4 = 192 ushort4 per row
  A4[rb]       = h;    // zh
  A4[rb + 64]  = h;    // zh
  A4[rb + 128] = lo;   // zl
}

// ---------------- kernel 2: wn2, split B_cat ----------------
__global__ __launch_bounds__(256) void k_prep_w(const float* __restrict__ w,
                                                float* __restrict__ wn2,
                                                ushort* __restrict__ Bcat) {
  const int row  = blockIdx.x * 4 + (threadIdx.x >> 6);
  const int lane = threadIdx.x & 63;
  float4 v = *(reinterpret_cast<const float4*>(w) + (size_t)row * 64 + lane);
  float s = v.x * v.x + v.y * v.y + v.z * v.z + v.w * v.w;
#pragma unroll
  for (int o = 32; o > 0; o >>= 1) s += __shfl_xor(s, o, 64);
  if (lane == 0) wn2[row] = s;
  ushort4 h  = make_ushort4(f2bf(v.x), f2bf(v.y), f2bf(v.z), f2bf(v.w));
  ushort4 lo = make_ushort4(f2bf(v.x - bf2f(h.x)), f2bf(v.y - bf2f(h.y)),
                            f2bf(v.z - bf2f(h.z)), f2bf(v.w - bf2f(h.w)));
  ushort4* B4 = reinterpret_cast<ushort4*>(Bcat);
  size_t rb = (size_t)row * 192 + lane;
  B4[rb]       = h;    // wh
  B4[rb + 64]  = lo;   // wl
  B4[rb + 128] = h;    // wh
}

// ---------------- kernel 3: high-occupancy MFMA GEMM, 128x256, BK=32 --------
// grid = 128 rt x 32 ct = 4096 blocks, 512 threads (8 waves, 2M x 4N,
// 64x64 out each -> acc 64 VGPR). LDS: 3 x 24KB buffers (A 8KB + B 16KB).
// Swizzle (64B rows, 4 x 16B granules): LDS[r][g] = G[r][g ^ ((r>>1)&3)]
// -> 2-way conflicts max (free per m136), both sides.
__global__ __launch_bounds__(512, 4) void k_coarse(const ushort* __restrict__ Acat,
                                                   const ushort* __restrict__ Bcat,
                                                   const float* __restrict__ wn2,
                                                   float* __restrict__ tm,
                                                   float* __restrict__ ts,
                                                   int* __restrict__ ti) {
  extern __shared__ char smem[];

  const int tid = threadIdx.x;
  const int l   = tid & 63;
  const int wv  = tid >> 6;
  const int wr  = wv >> 2;       // 0..1 -> rows wr*64
  const int wc  = wv & 3;        // 0..3 -> cols wc*64
  // XCD-aware 2D chunking: per XCD 512 blocks, 16 chunks (4x4) of 32 (4rt x 8ct)
  // chunk working set: A 4*128 rows (768KB) + B 8*256 rows (3MB) < 4MB L2.
  const int bid  = blockIdx.x;
  const int xcd  = bid & 7;
  const int q    = bid >> 3;               // 0..511
  const int chnk = q >> 5, wq = q & 31;    // 16 chunks of 32
  const int rt   = xcd * 16 + (chnk >> 2) * 4 + (wq >> 3);
  const int ct   = (chnk & 3) * 8 + (wq & 7);
  const int row0 = rt * BM;
  const int col0 = ct * BN;

  // ---- staging setup: 24 x 1KB units/tile (A:0-7, B:8-23), 3 per wave ----
  // unit u covers 16 rows; lane l -> row l>>2, LDS granule l&3,
  // source granule (l&3) ^ ((l>>3)&3)   [= (row>>1)&3 with row=l>>2]
  const int sgr = ((l & 3) ^ ((l >> 3) & 3)) * 16;
  const char* gsrc[3];
  unsigned    ldst[3];
#pragma unroll
  for (int s = 0; s < 3; ++s) {
    int u = wv * 3 + s;
    if (u < 8) {
      gsrc[s] = (const char*)Acat + (size_t)(row0 + u * 16 + (l >> 2)) * 1536 + sgr;
      ldst[s] = u * 1024;
    } else {
      gsrc[s] = (const char*)Bcat + (size_t)(col0 + (u - 8) * 16 + (l >> 2)) * 1536 + sgr;
      ldst[s] = 8192 + (u - 8) * 1024;
    }
  }
#define STAGE(t)                                                               \
  do {                                                                         \
    char* _b = smem + ((t) % 3) * 24576;                                       \
    _Pragma("unroll")                                                          \
    for (int s = 0; s < 3; ++s)                                                \
      gld16(_b + ldst[s] + (l & 63) * 16 - (l & 63) * 16 + (l >> 2) * 0 +      \
            ( (l & 3) * 16 + (l >> 2) * 64 ),                                  \
            gsrc[s] + (size_t)(t) * 64);                                       \
  } while (0)
  // NOTE: gld16 dest must be wave-uniform base + lane*16; lane l writes
  // offset l*16 automatically. Destination base = _b + ldst[s].
#undef STAGE
#define STAGE(t)                                                               \
  do {                                                                         \
    char* _b = smem + ((t) % 3) * 24576;                                       \
    _Pragma("unroll")                                                          \
    for (int s = 0; s < 3; ++s) gld16(_b + ldst[s], gsrc[s] + (size_t)(t) * 64); \
  } while (0)

  // ---- fragment read offsets ----
  const int lA  = l & 15;
  const int gsw = (lA >> 1) & 3;                      // (row>>1)&3
  const int gk  = (l >> 4) ^ gsw;                     // swizzled granule
  // A frag i: row wr*64+i*16+lA -> byte (wr*64+i*16+lA)*64 + gk*16
  const unsigned aOff = (unsigned)((wr * 64 + lA) * 64 + gk * 16);
  const unsigned bOff = (unsigned)(8192 + (wc * 64 + lA) * 64 + gk * 16);

  f32x4 acc[4][4];
#pragma unroll
  for (int i = 0; i < 4; ++i)
#pragma unroll
    for (int j = 0; j < 4; ++j) acc[i][j] = (f32x4){0.f, 0.f, 0.f, 0.f};

  // prologue: stage tiles 0,1 (order matters for vmcnt counting)
  STAGE(0);
  STAGE(1);

  for (int t = 0; t < NKT; ++t) {
    char* buf = smem + (t % 3) * 24576;
    // oldest 3 outstanding loads = stage(t), issued 2 tiles ago.
    if (t < NKT - 1) asm volatile("s_waitcnt vmcnt(3)" ::: "memory");
    else             asm volatile("s_waitcnt vmcnt(0)" ::: "memory");
    __builtin_amdgcn_s_barrier();
    __builtin_amdgcn_sched_barrier(0);
    if (t + 2 < NKT) STAGE(t + 2);   // writes buf (t+2)%3 == (t-1)%3: free

    bf16x8 af[4], bg[4];
#pragma unroll
    for (int i = 0; i < 4; ++i)
      af[i] = *(const bf16x8*)(buf + aOff + i * 1024);
#pragma unroll
    for (int j = 0; j < 4; ++j)
      bg[j] = *(const bf16x8*)(buf + bOff + j * 1024);
    __builtin_amdgcn_s_setprio(1);
#pragma unroll
    for (int i = 0; i < 4; ++i)
#pragma unroll
      for (int j = 0; j < 4; ++j)
        acc[i][j] = __builtin_amdgcn_mfma_f32_16x16x32_bf16(af[i], bg[j], acc[i][j], 0, 0, 0);
    __builtin_amdgcn_s_setprio(0);
  }
#undef STAGE

  // -------- epilogue: per-thread j-min, 16-lane shfl reduce, LDS merge -----
  float wnv[4];
#pragma unroll
  for (int n = 0; n < 4; ++n) wnv[n] = wn2[col0 + wc * 64 + n * 16 + lA];
  float4* red4 = (float4*)smem;    // [128][4] = 8KB
  __syncthreads();                 // all MFMA/LDS reads done before reuse

#pragma unroll
  for (int i = 0; i < 4; ++i) {
#pragma unroll
    for (int qq = 0; qq < 4; ++qq) {
      float m = FLT_MAX, s = FLT_MAX; int c = 0;
#pragma unroll
      for (int j = 0; j < 4; ++j) {
        float d = fmaf(-2.0f, acc[i][j][qq], wnv[j]);
        int cc = wc * 64 + j * 16 + lA;
        if (d < m) { s = m; m = d; c = cc; }
        else if (d < s) s = d;
      }
#pragma unroll
      for (int msk = 1; msk < 16; msk <<= 1) {
        float om = __shfl_xor(m, msk, 64);
        float os = __shfl_xor(s, msk, 64);
        int   oc = __shfl_xor(c, msk, 64);
        float ns = fminf(fminf(s, os), fmaxf(m, om));
        if (om < m || (om == m && oc < c)) { m = om; c = oc; }
        s = ns;
      }
      if (lA == 0) {
        int row = wr * 64 + i * 16 + (l >> 4) * 4 + qq;
        red4[row * 4 + wc] = (float4){m, s, __int_as_float(c), 0.f};
      }
    }
  }
  __syncthreads();
  if (tid < BM) {
    float4 e = red4[tid * 4];
    float gm = e.x, gs = e.y; int gc = __float_as_int(e.z);
#pragma unroll
    for (int k = 1; k < 4; ++k) {
      float4 ek = red4[tid * 4 + k];
      float om = ek.x, os = ek.y; int oc = __float_as_int(ek.z);
      float ns = fminf(fminf(gs, os), fmaxf(gm, om));
      if (om < gm || (om == gm && oc < gc)) { gm = om; gc = oc; }
      gs = ns;
    }
    size_t o = (size_t)ct * BT_ + row0 + tid;
    tm[o] = gm; ts[o] = gs; ti[o] = col0 + gc;
  }
}

// ---------------- kernel 4: combine tiles per row, flag ambiguous ----------------
__global__ __launch_bounds__(256) void k_combine(const float* __restrict__ tm,
                                                 const float* __restrict__ ts,
                                                 const int* __restrict__ ti,
                                                 int* __restrict__ idxf,
                                                 int* __restrict__ flagged,
                                                 int* __restrict__ count) {
  const int row = blockIdx.x * 256 + threadIdx.x;
  float m = FLT_MAX, s = FLT_MAX; int bi = 0x7fffffff;
  for (int t = 0; t < NTILES; ++t) {
    size_t o = (size_t)t * BT_ + row;
    float om = tm[o], os = ts[o]; int oi = ti[o];
    float nsv = fminf(fminf(s, os), fmaxf(m, om));
    if (om < m || (om == m && oi < bi)) { m = om; bi = oi; }
    s = nsv;
  }
  idxf[row] = bi;
  if (s - m <= THR_) {
    int p = atomicAdd(count, 1);
    flagged[p] = row;
  }
}

// ---------------- kernel 5: exact fp32 refinement of flagged rows ----------------
__global__ __launch_bounds__(128) void k_refine(const float* __restrict__ zn,
                                                const float* __restrict__ w,
                                                const float* __restrict__ wn2,
                                                const float* __restrict__ tm,
                                                const int* __restrict__ flagged,
                                                const int* __restrict__ count,
                                                int* __restrict__ idxf) {
  __shared__ float4 znr[64];
  __shared__ float tmr[32];
  __shared__ float m1s;
  __shared__ float wd[2];
  __shared__ int   wi[2];
  const int tid = threadIdx.x;
  const int cnt = *count;
  for (int f = blockIdx.x; f < cnt; f += gridDim.x) {
    __syncthreads();   // protect LDS reuse across iterations
    const int row = flagged[f];
    if (tid < 64) {
      znr[tid] = *(reinterpret_cast<const float4*>(zn) + (size_t)row * 64 + tid);
    }
    if (tid < 32) {
      float tv = tm[(size_t)tid * BT_ + row];
      tmr[tid] = tv;
      float mm = tv;
#pragma unroll
      for (int msk = 16; msk > 0; msk >>= 1) mm = fminf(mm, __shfl_xor(mm, msk, 64));
      if (tid == 0) m1s = mm;
    }
    __syncthreads();
    const float lim = m1s + THR_;
    float bd = FLT_MAX; int bi = 0x7fffffff;
    for (int t = 0; t < NTILES; ++t) {
      if (tmr[t] <= lim) {
#pragma unroll
        for (int h = 0; h < 2; ++h) {
          int c = t * BN + h * 128 + tid;
          const float4* wr4 = reinterpret_cast<const float4*>(w) + (size_t)c * 64;
          float d0 = 0.f, d1 = 0.f, d2 = 0.f, d3 = 0.f;
#pragma unroll
          for (int k4 = 0; k4 < 16; ++k4) {
            float4 a0 = znr[k4 * 4 + 0], b0 = wr4[k4 * 4 + 0];
            float4 a1 = znr[k4 * 4 + 1], b1 = wr4[k4 * 4 + 1];
            float4 a2 = znr[k4 * 4 + 2], b2 = wr4[k4 * 4 + 2];
            float4 a3 = znr[k4 * 4 + 3], b3 = wr4[k4 * 4 + 3];
            d0 = fmaf(a0.x, b0.x, d0); d0 = fmaf(a0.y, b0.y, d0);
            d0 = fmaf(a0.z, b0.z, d0); d0 = fmaf(a0.w, b0.w, d0);
            d1 = fmaf(a1.x, b1.x, d1); d1 = fmaf(a1.y, b1.y, d1);
            d1 = fmaf(a1.z, b1.z, d1); d1 = fmaf(a1.w, b1.w, d1);
            d2 = fmaf(a2.x, b2.x, d2); d2 = fmaf(a2.y, b2.y, d2);
            d2 = fmaf(a2.z, b2.z, d2); d2 = fmaf(a2.w, b2.w, d2);
            d3 = fmaf(a3.x, b3.x, d3); d3 = fmaf(a3.y, b3.y, d3);
            d3 = fmaf(a3.w, b3.w, d3); d3 = fmaf(a3.z, b3.z, d3);
          }
          float dot = (d0 + d1) + (d2 + d3);
          float d = fmaf(-2.0f, dot, wn2[c]);
          if (d < bd || (d == bd && c < bi)) { bd = d; bi = c; }
        }
      }
    }
#pragma unroll
    for (int msk = 1; msk < 64; msk <<= 1) {
      float od = __shfl_xor(bd, msk, 64);
      int   oi = __shfl_xor(bi, msk, 64);
      if (od < bd || (od == bd && oi < bi)) { bd = od; bi = oi; }
    }
    if ((tid & 63) == 0) { wd[tid >> 6] = bd; wi[tid >> 6] = bi; }
    __syncthreads();
    if (tid == 0) {
      float fd = wd[0]; int fi = wi[0];
      if (wd[1] < fd || (wd[1] == fd && wi[1] < fi)) { fd = wd[1]; fi = wi[1]; }
      idxf[row] = fi;
    }
  }
}

// ---------------- kernel 6: gather + loss partials (atomic-free) ----------------
__global__ __launch_bounds__(256) void k_gather(const float* __restrict__ zn,
                                                const float* __restrict__ w,
                                                const int* __restrict__ idxf,
                                                float* __restrict__ zq,
                                                float* __restrict__ idx_out,
                                                float* __restrict__ wpart) {
  const int row  = blockIdx.x * 4 + (threadIdx.x >> 6);
  const int lane = threadIdx.x & 63;
  const int bi = idxf[row];
  float4 cv = *(reinterpret_cast<const float4*>(w)  + (size_t)bi  * 64 + lane);
  float4 zv = *(reinterpret_cast<const float4*>(zn) + (size_t)row * 64 + lane);
  *(reinterpret_cast<float4*>(zq) + (size_t)row * 64 + lane) = cv;
  float dx = cv.x - zv.x, dy = cv.y - zv.y, dz = cv.z - zv.z, dw = cv.w - zv.w;
  float s = dx * dx + dy * dy + dz * dz + dw * dw;
#pragma unroll
  for (int o = 32; o > 0; o >>= 1) s += __shfl_xor(s, o, 64);
  if (lane == 0) {
    wpart[row] = s;
    idx_out[row] = (float)bi;
  }
}

// ---------------- kernel 7: final loss reduction ----------------
__global__ __launch_bounds__(256) void k_final(const float* __restrict__ wpart,
                                               float* __restrict__ loss_out) {
  __shared__ float wsum[4];
  float s = 0.f;
  for (int i = threadIdx.x; i < BT_; i += 256) s += wpart[i];
#pragma unroll
  for (int o = 32; o > 0; o >>= 1) s += __shfl_xor(s, o, 64);
  if ((threadIdx.x & 63) == 0) wsum[threadIdx.x >> 6] = s;
  __syncthreads();
  if (threadIdx.x == 0)
    loss_out[0] = BETA_ * ((wsum[0] + wsum[1]) + (wsum[2] + wsum[3])) *
                  (1.0f / (float)(BT_ * D_));
}

extern "C" void kernel_launch(void* const* d_in, const int* in_sizes, int n_in,
                              void* d_out, int out_size, void* d_ws, size_t ws_size,
                              hipStream_t stream) {
  const float* z = (const float*)d_in[0];
  const float* w = (const float*)d_in[1];

  float* out      = (float*)d_out;
  float* zq       = out;
  float* loss_out = out + (size_t)BT_ * D_;
  float* idx_out  = loss_out + 1;

  char* wsb = (char*)d_ws;
  float*  zn      = (float*)(wsb);                         // 16 MB
  ushort* Acat    = (ushort*)(wsb + 16777216);             // 24 MB
  ushort* Bcat    = (ushort*)(wsb + 41943040);             // 12 MB
  float*  tm      = (float*)(wsb + 54525952);              // 2 MB used
  float*  ts      = (float*)(wsb + 58720256);              // 2 MB used (reused as wpart)
  int*    ti      = (int*)(wsb + 62914560);                // 2 MB used
  float*  wn2     = (float*)(wsb + 67108864);              // 32 KB
  int*    idxf    = (int*)(wsb + 67141632);                // 64 KB
  int*    flagged = (int*)(wsb + 67207168);                // 64 KB
  int*    count   = (int*)(wsb + 67272704);
  float*  wpart   = ts;   // ts is dead after k_combine

  hipFuncSetAttribute((const void*)k_coarse,
                      hipFuncAttributeMaxDynamicSharedMemorySize, 73728);

  hipMemsetAsync(count, 0, 4, stream);
  k_prep_z<<<BT_ / 4, 256, 0, stream>>>(z, zn, Acat);
  k_prep_w<<<N_ / 4, 256, 0, stream>>>(w, wn2, Bcat);
  k_coarse<<<(BT_ / BM) * NTILES, 512, 73728, stream>>>(Acat, Bcat, wn2, tm, ts, ti);
  k_combine<<<BT_ / 256, 256, 0, stream>>>(tm, ts, ti, idxf, flagged, count);
  k_refine<<<2048, 128, 0, stream>>>(zn, w, wn2, tm, flagged, count, idxf);
  k_gather<<<BT_ / 4, 256, 0, stream>>>(zn, w, idxf, zq, idx_out, wpart);
  k_final<<<1, 256, 0, stream>>>(wpart, loss_out);
}

// Round 9
// 318.334 us; speedup vs baseline: 1.2508x; 1.1081x over previous
//
#include <hip/hip_runtime.h>
#include <float.h>
#include <math.h>

// NormEMAVectorQuantizer via split-bf16 MFMA + exact fp32 refinement.
// z (8,2048,256) f32, weight (8192,256) f32 (unit rows).
// out = [ z_q (16384*256) | loss (1) | indices (16384, as float) ]
//
// Round-9: K-loop identical to r8 (128x256, BK=32, 8 waves 2Mx4N 64x64,
// triple-buffer 72KB, launch_bounds(512,4) -> 2 blocks/CU, vmcnt(3)).
// Epilogue rebuilt: the r8 shuffle-butterfly was ~50% of all LDS-pipe
// traffic (192 ds_bpermute/wave). Now: j-min -> ONE shfl_xor(8) merge ->
// scatter to stride-33 LDS planes (reuse staging) -> 512-thread scan.

#define BT_ 16384
#define D_  256
#define N_  8192
#define BETA_ 1.0f
#define THR_ 5e-4f

#define BM 128
#define BN 256
#define NKT 24           // 768 / 32 K-tiles
#define NTILES 32        // N_ / BN

typedef __attribute__((ext_vector_type(8))) short bf16x8;
typedef __attribute__((ext_vector_type(4))) float f32x4;

__device__ __forceinline__ void gld16(void* lds, const void* g) {
  __builtin_amdgcn_global_load_lds(
      (const __attribute__((address_space(1))) void*)g,
      (__attribute__((address_space(3))) void*)lds, 16, 0, 0);
}

__device__ __forceinline__ unsigned short f2bf(float x) {
  unsigned u = __float_as_uint(x);
  u += 0x7FFFu + ((u >> 16) & 1u);
  return (unsigned short)(u >> 16);
}
__device__ __forceinline__ float bf2f(unsigned short h) {
  return __uint_as_float(((unsigned)h) << 16);
}

// ---------------- kernel 1: normalize z, store zn + split A_cat ----------------
__global__ __launch_bounds__(256) void k_prep_z(const float* __restrict__ z,
                                                float* __restrict__ zn,
                                                ushort* __restrict__ Acat) {
  const int row  = blockIdx.x * 4 + (threadIdx.x >> 6);
  const int lane = threadIdx.x & 63;
  float4 v = *(reinterpret_cast<const float4*>(z) + (size_t)row * 64 + lane);
  float s = v.x * v.x + v.y * v.y + v.z * v.z + v.w * v.w;
#pragma unroll
  for (int o = 32; o > 0; o >>= 1) s += __shfl_xor(s, o, 64);
  float dn = fmaxf(sqrtf(s), 1e-12f);
  v.x /= dn; v.y /= dn; v.z /= dn; v.w /= dn;
  *(reinterpret_cast<float4*>(zn) + (size_t)row * 64 + lane) = v;
  ushort4 h  = make_ushort4(f2bf(v.x), f2bf(v.y), f2bf(v.z), f2bf(v.w));
  ushort4 lo = make_ushort4(f2bf(v.x - bf2f(h.x)), f2bf(v.y - bf2f(h.y)),
                            f2bf(v.z - bf2f(h.z)), f2bf(v.w - bf2f(h.w)));
  ushort4* A4 = reinterpret_cast<ushort4*>(Acat);
  size_t rb = (size_t)row * 192 + lane;   // 768/4 = 192 ushort4 per row
  A4[rb]       = h;    // zh
  A4[rb + 64]  = h;    // zh
  A4[rb + 128] = lo;   // zl
}

// ---------------- kernel 2: wn2, split B_cat ----------------
__global__ __launch_bounds__(256) void k_prep_w(const float* __restrict__ w,
                                                float* __restrict__ wn2,
                                                ushort* __restrict__ Bcat) {
  const int row  = blockIdx.x * 4 + (threadIdx.x >> 6);
  const int lane = threadIdx.x & 63;
  float4 v = *(reinterpret_cast<const float4*>(w) + (size_t)row * 64 + lane);
  float s = v.x * v.x + v.y * v.y + v.z * v.z + v.w * v.w;
#pragma unroll
  for (int o = 32; o > 0; o >>= 1) s += __shfl_xor(s, o, 64);
  if (lane == 0) wn2[row] = s;
  ushort4 h  = make_ushort4(f2bf(v.x), f2bf(v.y), f2bf(v.z), f2bf(v.w));
  ushort4 lo = make_ushort4(f2bf(v.x - bf2f(h.x)), f2bf(v.y - bf2f(h.y)),
                            f2bf(v.z - bf2f(h.z)), f2bf(v.w - bf2f(h.w)));
  ushort4* B4 = reinterpret_cast<ushort4*>(Bcat);
  size_t rb = (size_t)row * 192 + lane;
  B4[rb]       = h;    // wh
  B4[rb + 64]  = lo;   // wl
  B4[rb + 128] = h;    // wh
}

// ---------------- kernel 3: high-occupancy MFMA GEMM, 128x256, BK=32 --------
// grid = 128 rt x 32 ct = 4096 blocks, 512 threads (8 waves, 2M x 4N,
// 64x64 out each -> acc 64 VGPR). LDS: 3 x 24KB buffers (A 8KB + B 16KB).
// Swizzle (64B rows, 4 x 16B granules): LDS[r][g] = G[r][g ^ ((r>>1)&3)].
__global__ __launch_bounds__(512, 4) void k_coarse(const ushort* __restrict__ Acat,
                                                   const ushort* __restrict__ Bcat,
                                                   const float* __restrict__ wn2,
                                                   float* __restrict__ tm,
                                                   float* __restrict__ ts,
                                                   int* __restrict__ ti) {
  extern __shared__ char smem[];

  const int tid = threadIdx.x;
  const int l   = tid & 63;
  const int wv  = tid >> 6;
  const int wr  = wv >> 2;       // 0..1 -> rows wr*64
  const int wc  = wv & 3;        // 0..3 -> cols wc*64
  // XCD-aware 2D chunking: per XCD 512 blocks, 16 chunks of 32 as 8rt x 4ct
  // chunk working set: A 8*128 rows (1.5MB) + B 4*256 rows (1.5MB) < 4MB L2.
  const int bid  = blockIdx.x;
  const int xcd  = bid & 7;
  const int q    = bid >> 3;               // 0..511
  const int chnk = q >> 5, wq = q & 31;    // 16 chunks of 32
  const int rt   = xcd * 16 + (chnk >> 3) * 8 + (wq >> 2);
  const int ct   = (chnk & 7) * 4 + (wq & 3);
  const int row0 = rt * BM;
  const int col0 = ct * BN;

  // ---- staging setup: 24 x 1KB units/tile (A:0-7, B:8-23), 3 per wave ----
  // unit u covers 16 rows; lane l -> row l>>2, LDS granule l&3,
  // source granule (l&3) ^ ((l>>3)&3)   [= (row>>1)&3 with row=l>>2]
  const int sgr = ((l & 3) ^ ((l >> 3) & 3)) * 16;
  const char* gsrc[3];
  unsigned    ldst[3];
#pragma unroll
  for (int s = 0; s < 3; ++s) {
    int u = wv * 3 + s;
    if (u < 8) {
      gsrc[s] = (const char*)Acat + (size_t)(row0 + u * 16 + (l >> 2)) * 1536 + sgr;
      ldst[s] = u * 1024;
    } else {
      gsrc[s] = (const char*)Bcat + (size_t)(col0 + (u - 8) * 16 + (l >> 2)) * 1536 + sgr;
      ldst[s] = 8192 + (u - 8) * 1024;
    }
  }
#define STAGE(t)                                                               \
  do {                                                                         \
    char* _b = smem + ((t) % 3) * 24576;                                       \
    _Pragma("unroll")                                                          \
    for (int s = 0; s < 3; ++s) gld16(_b + ldst[s], gsrc[s] + (size_t)(t) * 64); \
  } while (0)

  // ---- fragment read offsets ----
  const int lA  = l & 15;
  const int gsw = (lA >> 1) & 3;                      // (row>>1)&3
  const int gk  = (l >> 4) ^ gsw;                     // swizzled granule
  const unsigned aOff = (unsigned)((wr * 64 + lA) * 64 + gk * 16);
  const unsigned bOff = (unsigned)(8192 + (wc * 64 + lA) * 64 + gk * 16);

  f32x4 acc[4][4];
#pragma unroll
  for (int i = 0; i < 4; ++i)
#pragma unroll
    for (int j = 0; j < 4; ++j) acc[i][j] = (f32x4){0.f, 0.f, 0.f, 0.f};

  // prologue: stage tiles 0,1
  STAGE(0);
  STAGE(1);

  for (int t = 0; t < NKT; ++t) {
    char* buf = smem + (t % 3) * 24576;
    // oldest 3 outstanding loads = stage(t), issued 2 tiles ago.
    if (t < NKT - 1) asm volatile("s_waitcnt vmcnt(3)" ::: "memory");
    else             asm volatile("s_waitcnt vmcnt(0)" ::: "memory");
    __builtin_amdgcn_s_barrier();
    __builtin_amdgcn_sched_barrier(0);
    if (t + 2 < NKT) STAGE(t + 2);   // writes buf (t+2)%3 == (t-1)%3: free

    bf16x8 af[4], bg[4];
#pragma unroll
    for (int i = 0; i < 4; ++i)
      af[i] = *(const bf16x8*)(buf + aOff + i * 1024);
#pragma unroll
    for (int j = 0; j < 4; ++j)
      bg[j] = *(const bf16x8*)(buf + bOff + j * 1024);
    __builtin_amdgcn_s_setprio(1);
#pragma unroll
    for (int i = 0; i < 4; ++i)
#pragma unroll
      for (int j = 0; j < 4; ++j)
        acc[i][j] = __builtin_amdgcn_mfma_f32_16x16x32_bf16(af[i], bg[j], acc[i][j], 0, 0, 0);
    __builtin_amdgcn_s_setprio(0);
  }
#undef STAGE

  // -------- epilogue: j-min -> one shfl_xor(8) -> LDS planes -> scan -------
  // planes (stride 33 words vs 32 rows -> conflict-free-ish):
  //   pm [128][33] f32 @0, ps @16896, pc @33792 (50.7KB, reuses staging LDS)
  float wnv[4];
#pragma unroll
  for (int n = 0; n < 4; ++n) wnv[n] = wn2[col0 + wc * 64 + n * 16 + lA];
  float* pm = (float*)smem;
  float* ps = (float*)(smem + 16896);
  int*   pc = (int*)(smem + 33792);
  __syncthreads();   // all K-loop LDS reads complete before reuse

#pragma unroll
  for (int i = 0; i < 4; ++i) {
#pragma unroll
    for (int qq = 0; qq < 4; ++qq) {
      float m = FLT_MAX, s = FLT_MAX; int c = 0;
#pragma unroll
      for (int j = 0; j < 4; ++j) {
        float d = fmaf(-2.0f, acc[i][j][qq], wnv[j]);
        int cc = wc * 64 + j * 16 + lA;
        if (d < m) { s = m; m = d; c = cc; }
        else if (d < s) s = d;
      }
      // one merge round across lane^8 (lA and lA+8 hold disjoint cols)
      float om = __shfl_xor(m, 8, 64);
      float os = __shfl_xor(s, 8, 64);
      int   oc = __shfl_xor(c, 8, 64);
      float ns = fminf(fminf(s, os), fmaxf(m, om));
      if (om < m || (om == m && oc < c)) { m = om; c = oc; }
      s = ns;
      if ((l & 8) == 0) {
        int row = wr * 64 + i * 16 + (l >> 4) * 4 + qq;
        int w33 = row * 33 + wc * 8 + (l & 7);
        pm[w33] = m; ps[w33] = s; pc[w33] = c;
      }
    }
  }
  __syncthreads();
  {
    const int row = tid >> 2;      // 0..127
    const int qd  = tid & 3;       // quarter: 8 slots each
    float gm = FLT_MAX, gs = FLT_MAX; int gc = 0x7fffffff;
#pragma unroll
    for (int k = 0; k < 8; ++k) {
      int w33 = row * 33 + qd * 8 + k;
      float m = pm[w33], s = ps[w33]; int c = pc[w33];
      float ns = fminf(fminf(gs, s), fmaxf(gm, m));
      if (m < gm || (m == gm && c < gc)) { gm = m; gc = c; }
      gs = ns;
    }
#pragma unroll
    for (int msk = 1; msk <= 2; msk <<= 1) {
      float om = __shfl_xor(gm, msk, 64);
      float os = __shfl_xor(gs, msk, 64);
      int   oc = __shfl_xor(gc, msk, 64);
      float ns = fminf(fminf(gs, os), fmaxf(gm, om));
      if (om < gm || (om == gm && oc < gc)) { gm = om; gc = oc; }
      gs = ns;
    }
    if (qd == 0) {
      size_t o = (size_t)ct * BT_ + row0 + row;
      tm[o] = gm; ts[o] = gs; ti[o] = col0 + gc;
    }
  }
}

// ---------------- kernel 4: combine tiles per row, flag ambiguous ----------------
__global__ __launch_bounds__(256) void k_combine(const float* __restrict__ tm,
                                                 const float* __restrict__ ts,
                                                 const int* __restrict__ ti,
                                                 int* __restrict__ idxf,
                                                 int* __restrict__ flagged,
                                                 int* __restrict__ count) {
  const int row = blockIdx.x * 256 + threadIdx.x;
  float m = FLT_MAX, s = FLT_MAX; int bi = 0x7fffffff;
  for (int t = 0; t < NTILES; ++t) {
    size_t o = (size_t)t * BT_ + row;
    float om = tm[o], os = ts[o]; int oi = ti[o];
    float nsv = fminf(fminf(s, os), fmaxf(m, om));
    if (om < m || (om == m && oi < bi)) { m = om; bi = oi; }
    s = nsv;
  }
  idxf[row] = bi;
  if (s - m <= THR_) {
    int p = atomicAdd(count, 1);
    flagged[p] = row;
  }
}

// ---------------- kernel 5: exact fp32 refinement of flagged rows ----------------
__global__ __launch_bounds__(128) void k_refine(const float* __restrict__ zn,
                                                const float* __restrict__ w,
                                                const float* __restrict__ wn2,
                                                const float* __restrict__ tm,
                                                const int* __restrict__ flagged,
                                                const int* __restrict__ count,
                                                int* __restrict__ idxf) {
  __shared__ float4 znr[64];
  __shared__ float tmr[32];
  __shared__ float m1s;
  __shared__ float wd[2];
  __shared__ int   wi[2];
  const int tid = threadIdx.x;
  const int cnt = *count;
  for (int f = blockIdx.x; f < cnt; f += gridDim.x) {
    __syncthreads();   // protect LDS reuse across iterations
    const int row = flagged[f];
    if (tid < 64) {
      znr[tid] = *(reinterpret_cast<const float4*>(zn) + (size_t)row * 64 + tid);
    }
    if (tid < 32) {
      float tv = tm[(size_t)tid * BT_ + row];
      tmr[tid] = tv;
      float mm = tv;
#pragma unroll
      for (int msk = 16; msk > 0; msk >>= 1) mm = fminf(mm, __shfl_xor(mm, msk, 64));
      if (tid == 0) m1s = mm;
    }
    __syncthreads();
    const float lim = m1s + THR_;
    float bd = FLT_MAX; int bi = 0x7fffffff;
    for (int t = 0; t < NTILES; ++t) {
      if (tmr[t] <= lim) {
#pragma unroll
        for (int h = 0; h < 2; ++h) {
          int c = t * BN + h * 128 + tid;
          const float4* wr4 = reinterpret_cast<const float4*>(w) + (size_t)c * 64;
          float d0 = 0.f, d1 = 0.f, d2 = 0.f, d3 = 0.f;
#pragma unroll
          for (int k4 = 0; k4 < 16; ++k4) {
            float4 a0 = znr[k4 * 4 + 0], b0 = wr4[k4 * 4 + 0];
            float4 a1 = znr[k4 * 4 + 1], b1 = wr4[k4 * 4 + 1];
            float4 a2 = znr[k4 * 4 + 2], b2 = wr4[k4 * 4 + 2];
            float4 a3 = znr[k4 * 4 + 3], b3 = wr4[k4 * 4 + 3];
            d0 = fmaf(a0.x, b0.x, d0); d0 = fmaf(a0.y, b0.y, d0);
            d0 = fmaf(a0.z, b0.z, d0); d0 = fmaf(a0.w, b0.w, d0);
            d1 = fmaf(a1.x, b1.x, d1); d1 = fmaf(a1.y, b1.y, d1);
            d1 = fmaf(a1.z, b1.z, d1); d1 = fmaf(a1.w, b1.w, d1);
            d2 = fmaf(a2.x, b2.x, d2); d2 = fmaf(a2.y, b2.y, d2);
            d2 = fmaf(a2.z, b2.z, d2); d2 = fmaf(a2.w, b2.w, d2);
            d3 = fmaf(a3.x, b3.x, d3); d3 = fmaf(a3.y, b3.y, d3);
            d3 = fmaf(a3.z, b3.z, d3); d3 = fmaf(a3.w, b3.w, d3);
          }
          float dot = (d0 + d1) + (d2 + d3);
          float d = fmaf(-2.0f, dot, wn2[c]);
          if (d < bd || (d == bd && c < bi)) { bd = d; bi = c; }
        }
      }
    }
#pragma unroll
    for (int msk = 1; msk < 64; msk <<= 1) {
      float od = __shfl_xor(bd, msk, 64);
      int   oi = __shfl_xor(bi, msk, 64);
      if (od < bd || (od == bd && oi < bi)) { bd = od; bi = oi; }
    }
    if ((tid & 63) == 0) { wd[tid >> 6] = bd; wi[tid >> 6] = bi; }
    __syncthreads();
    if (tid == 0) {
      float fd = wd[0]; int fi = wi[0];
      if (wd[1] < fd || (wd[1] == fd && wi[1] < fi)) { fd = wd[1]; fi = wi[1]; }
      idxf[row] = fi;
    }
  }
}

// ---------------- kernel 6: gather + loss partials (atomic-free) ----------------
__global__ __launch_bounds__(256) void k_gather(const float* __restrict__ zn,
                                                const float* __restrict__ w,
                                                const int* __restrict__ idxf,
                                                float* __restrict__ zq,
                                                float* __restrict__ idx_out,
                                                float* __restrict__ wpart) {
  const int row  = blockIdx.x * 4 + (threadIdx.x >> 6);
  const int lane = threadIdx.x & 63;
  const int bi = idxf[row];
  float4 cv = *(reinterpret_cast<const float4*>(w)  + (size_t)bi  * 64 + lane);
  float4 zv = *(reinterpret_cast<const float4*>(zn) + (size_t)row * 64 + lane);
  *(reinterpret_cast<float4*>(zq) + (size_t)row * 64 + lane) = cv;
  float dx = cv.x - zv.x, dy = cv.y - zv.y, dz = cv.z - zv.z, dw = cv.w - zv.w;
  float s = dx * dx + dy * dy + dz * dz + dw * dw;
#pragma unroll
  for (int o = 32; o > 0; o >>= 1) s += __shfl_xor(s, o, 64);
  if (lane == 0) {
    wpart[row] = s;
    idx_out[row] = (float)bi;
  }
}

// ---------------- kernel 7: final loss reduction ----------------
__global__ __launch_bounds__(256) void k_final(const float* __restrict__ wpart,
                                               float* __restrict__ loss_out) {
  __shared__ float wsum[4];
  float s = 0.f;
  for (int i = threadIdx.x; i < BT_; i += 256) s += wpart[i];
#pragma unroll
  for (int o = 32; o > 0; o >>= 1) s += __shfl_xor(s, o, 64);
  if ((threadIdx.x & 63) == 0) wsum[threadIdx.x >> 6] = s;
  __syncthreads();
  if (threadIdx.x == 0)
    loss_out[0] = BETA_ * ((wsum[0] + wsum[1]) + (wsum[2] + wsum[3])) *
                  (1.0f / (float)(BT_ * D_));
}

extern "C" void kernel_launch(void* const* d_in, const int* in_sizes, int n_in,
                              void* d_out, int out_size, void* d_ws, size_t ws_size,
                              hipStream_t stream) {
  const float* z = (const float*)d_in[0];
  const float* w = (const float*)d_in[1];

  float* out      = (float*)d_out;
  float* zq       = out;
  float* loss_out = out + (size_t)BT_ * D_;
  float* idx_out  = loss_out + 1;

  char* wsb = (char*)d_ws;
  float*  zn      = (float*)(wsb);                         // 16 MB
  ushort* Acat    = (ushort*)(wsb + 16777216);             // 24 MB
  ushort* Bcat    = (ushort*)(wsb + 41943040);             // 12 MB
  float*  tm      = (float*)(wsb + 54525952);              // 2 MB used
  float*  ts      = (float*)(wsb + 58720256);              // 2 MB used (reused as wpart)
  int*    ti      = (int*)(wsb + 62914560);                // 2 MB used
  float*  wn2     = (float*)(wsb + 67108864);              // 32 KB
  int*    idxf    = (int*)(wsb + 67141632);                // 64 KB
  int*    flagged = (int*)(wsb + 67207168);                // 64 KB
  int*    count   = (int*)(wsb + 67272704);
  float*  wpart   = ts;   // ts is dead after k_combine

  hipFuncSetAttribute((const void*)k_coarse,
                      hipFuncAttributeMaxDynamicSharedMemorySize, 73728);

  hipMemsetAsync(count, 0, 4, stream);
  k_prep_z<<<BT_ / 4, 256, 0, stream>>>(z, zn, Acat);
  k_prep_w<<<N_ / 4, 256, 0, stream>>>(w, wn2, Bcat);
  k_coarse<<<(BT_ / BM) * NTILES, 512, 73728, stream>>>(Acat, Bcat, wn2, tm, ts, ti);
  k_combine<<<BT_ / 256, 256, 0, stream>>>(tm, ts, ti, idxf, flagged, count);
  k_refine<<<2048, 128, 0, stream>>>(zn, w, wn2, tm, flagged, count, idxf);
  k_gather<<<BT_ / 4, 256, 0, stream>>>(zn, w, idxf, zq, idx_out, wpart);
  k_final<<<1, 256, 0, stream>>>(wpart, loss_out);
}